// Round 18
// baseline (164.366 us; speedup 1.0000x reference)
//
#include <hip/hip_runtime.h>
#include <hip/hip_bf16.h>
#include <stdint.h>

#define N_TOK 16384
#define HDIM  1024
#define NE    8

#define BM 128
#define BN 128
#define BK 64
#define NKT (HDIM / BK)            // 16
#define NT_N (HDIM / BN)           // 8
#define MAXTILES (N_TOK / BM + NE) // 136 worst-case row-tiles (136 % 8 == 0)
#define GRID_GEMM (MAXTILES * NT_N) // 1088

typedef __attribute__((ext_vector_type(8))) short          bf16x8;
typedef __attribute__((ext_vector_type(8))) unsigned short ushort8;
typedef __attribute__((ext_vector_type(4))) unsigned short ushort4v;
typedef __attribute__((ext_vector_type(4))) float          f32x4;

__device__ __forceinline__ unsigned short f2bf(float f) {
  union { float f; uint32_t u; } c; c.f = f;
  uint32_t u = c.u;
  uint32_t r = (u + 0x7fffu + ((u >> 16) & 1u)) >> 16;
  return (unsigned short)r;
}

__device__ __forceinline__ void gload_lds16(const void* g, void* l) {
  __builtin_amdgcn_global_load_lds((const __attribute__((address_space(1))) void*)g,
                                   (__attribute__((address_space(3))) void*)l, 16, 0, 0);
}

__device__ __forceinline__ void expert_range(const int* __restrict__ counts, int e,
                                             int& base, int& cnt) {
  int run = 0; base = 0; cnt = 0;
#pragma unroll
  for (int i = 0; i < NE; ++i) {
    int c = counts[i];
    if (i == e) { base = run; cnt = c; }
    run += c;
  }
}

// ---------------------------------------------------------------------------
// Gate (r16 body, weight-cvt REMOVED from gate blocks) + 1024 APPENDED pure
// cvt blocks (bid>=4096): each converts a 16384-f32 slice of w1/w2 and exits.
// Appended blocks backfill CUs as latency-bound gate blocks drain (tail
// overlap); prepended placement (r14) serialized instead. counts zeroed by
// block 0. Cvt blocks early-return BEFORE the barrier (no sync hazard).
// ---------------------------------------------------------------------------
__global__ __launch_bounds__(256) void gate_kernel(
    const float* __restrict__ tokens, const float* __restrict__ gate_w,
    const float* __restrict__ w1f, const float* __restrict__ w2f,
    unsigned short* __restrict__ tokB, unsigned short* __restrict__ w1B,
    unsigned short* __restrict__ w2B, int* __restrict__ eid,
    int* __restrict__ counts)
{
  int t = threadIdx.x;

  if (blockIdx.x >= 4096) {
    // pure weight-cvt block: 16384 f32 -> bf16 (4 passes x 16 elems/thread)
    int cb = blockIdx.x - 4096;             // 0..1023
    const float* wsrc = (cb < 512) ? w1f : w2f;
    unsigned short* wdst = (cb < 512) ? w1B : w2B;
    size_t s0 = (size_t)(cb & 511) * 16384;
#pragma unroll
    for (int p = 0; p < 4; ++p) {
      size_t i0 = s0 + (size_t)p * 4096 + (size_t)t * 16;
      float4 fa0 = *(const float4*)(wsrc + i0);
      float4 fb0 = *(const float4*)(wsrc + i0 + 4);
      float4 fa1 = *(const float4*)(wsrc + i0 + 8);
      float4 fb1 = *(const float4*)(wsrc + i0 + 12);
      ushort8 o0, o1;
      o0[0] = f2bf(fa0.x); o0[1] = f2bf(fa0.y); o0[2] = f2bf(fa0.z); o0[3] = f2bf(fa0.w);
      o0[4] = f2bf(fb0.x); o0[5] = f2bf(fb0.y); o0[6] = f2bf(fb0.z); o0[7] = f2bf(fb0.w);
      o1[0] = f2bf(fa1.x); o1[1] = f2bf(fa1.y); o1[2] = f2bf(fa1.z); o1[3] = f2bf(fa1.w);
      o1[4] = f2bf(fb1.x); o1[5] = f2bf(fb1.y); o1[6] = f2bf(fb1.z); o1[7] = f2bf(fb1.w);
      *(ushort8*)(wdst + i0)     = o0;
      *(ushort8*)(wdst + i0 + 8) = o1;
    }
    return;
  }

  __shared__ float gw[NE * HDIM];  // 32 KB

  if (blockIdx.x == 0 && t < NE) counts[t] = 0;

  // stage gate_w -> LDS (8 x 16B per thread, async DMA)
#pragma unroll
  for (int h = 0; h < 8; ++h) {
    size_t f = (size_t)h * 1024 + (size_t)t * 4;
    gload_lds16(gate_w + f, gw + f);
  }

  // token loads + bf16 store
  int wid  = t >> 6;
  int lane = t & 63;
  int n    = blockIdx.x * 4 + wid;

  const float* trow = tokens + (size_t)n * HDIM;
  float4 x[4];
#pragma unroll
  for (int i = 0; i < 4; ++i)
    x[i] = *(const float4*)(trow + i * 256 + lane * 4);

  unsigned short* drow = tokB + (size_t)n * HDIM;
#pragma unroll
  for (int i = 0; i < 4; ++i) {
    ushort4v o;
    o[0] = f2bf(x[i].x); o[1] = f2bf(x[i].y);
    o[2] = f2bf(x[i].z); o[3] = f2bf(x[i].w);
    *(ushort4v*)(drow + i * 256 + lane * 4) = o;
  }

  __syncthreads();  // gate_w staged (drains all outstanding loads)

  // gate math from LDS (f64 accum)
  double acc[NE];
#pragma unroll
  for (int e = 0; e < NE; ++e) {
    const float* grow = gw + e * HDIM;
    double a = 0.0;
#pragma unroll
    for (int i = 0; i < 4; ++i) {
      float4 g = *(const float4*)(grow + i * 256 + lane * 4);
      a += (double)x[i].x * g.x + (double)x[i].y * g.y
         + (double)x[i].z * g.z + (double)x[i].w * g.w;
    }
    acc[e] = a;
  }
#pragma unroll
  for (int off = 32; off; off >>= 1) {
#pragma unroll
    for (int e = 0; e < NE; ++e) acc[e] += __shfl_xor(acc[e], off);
  }
  if (lane == 0) {
    int best = 0; double bv = acc[0];
#pragma unroll
    for (int e = 1; e < NE; ++e) if (acc[e] > bv) { bv = acc[e]; best = e; }
    eid[n] = best;
  }
}

// ---------------------------------------------------------------------------
// Rank: LDS histogram per 256-token block; 8 global atomics per block.
// ---------------------------------------------------------------------------
__global__ __launch_bounds__(256) void rank_kernel(
    const int* __restrict__ eid, int* __restrict__ rank, int* __restrict__ counts)
{
  __shared__ int h[NE];
  __shared__ int bbase[NE];
  int t = threadIdx.x;
  int n = blockIdx.x * 256 + t;
  if (t < NE) h[t] = 0;
  __syncthreads();
  int e = eid[n];
  int r = atomicAdd(&h[e], 1);
  __syncthreads();
  if (t < NE) bbase[t] = atomicAdd(&counts[t], h[t]);
  __syncthreads();
  rank[n] = bbase[e] + r;
}

// perm + tilemap fused (r11-verified): scatter token index; block 0 thread 0
// also emits the compact active-tile list for the GEMM grid.
__global__ __launch_bounds__(256) void perm_kernel(
    const int* __restrict__ counts, const int* __restrict__ eid,
    const int* __restrict__ rank, int* __restrict__ topos,
    int* __restrict__ tmeta)
{
  __shared__ int off[NE];
  int t = threadIdx.x;
  if (t == 0) {
    int run = 0;
#pragma unroll
    for (int e = 0; e < NE; ++e) { off[e] = run; run += counts[e]; }
  }
  __syncthreads();
  int n = blockIdx.x * 256 + t;
  topos[off[eid[n]] + rank[n]] = n;
  if (blockIdx.x == 0 && t == 0) {
    int idx = 0;
    for (int e = 0; e < NE; ++e) {
      int ntile = (counts[e] + BM - 1) / BM;
      for (int mt = 0; mt < ntile; ++mt) tmeta[1 + idx++] = (mt << 3) | e;
    }
    tmeta[0] = idx;
  }
}

// ---------------------------------------------------------------------------
// Grouped GEMM, r5-verified m97 structure: 128x128 tile, BK=64, 4 waves (2x2),
// single 32KB LDS buffer, 2 syncthreads per K-tile, compiler-scheduled waits.
// Both-sides chunk-XOR LDS swizzle (0 conflicts). XCD-chunked block swizzle
// (17 consecutive tiles ~ one expert per XCD; FETCH 141->36 MB).
// ---------------------------------------------------------------------------
#define GEMM_PREAMBLE()                                                        \
  int bid = blockIdx.x;                                                        \
  int logical = (bid & 7) * (GRID_GEMM / 8) + (bid >> 3);                      \
  int tile = logical >> 3;                                                     \
  int nt   = logical & 7;                                                      \
  if (tile >= tmeta[0]) return;                                                \
  int ent = tmeta[1 + tile];                                                   \
  int e = ent & 7, mt = ent >> 3;                                              \
  int base, cnt;                                                               \
  expert_range(counts, e, base, cnt);                                          \
  __shared__ unsigned short Alds[BM * BK];                                     \
  __shared__ unsigned short Blds[BN * BK];                                     \
  int t    = threadIdx.x;                                                      \
  int kc   = t & 7;            /* 16B chunk within row */                      \
  int rowi = t >> 3;           /* 0..31 */                                     \
  int sch  = kc ^ (rowi & 7);  /* inverse-swizzled source chunk */             \
  int lane = t & 63, wid = t >> 6;                                             \
  int wr = wid >> 1, wc = wid & 1;                                             \
  f32x4 acc[4][4] = {};                                                        \
  int arow0 = wr * 64 + (lane & 15);                                           \
  int brow0 = wc * 64 + (lane & 15);                                           \
  int hi    = lane >> 4;       /* 0..3 */                                      \
  int xo    = lane & 7;        /* read-side XOR */

#define GEMM_STAGE(kt)                                                         \
  _Pragma("unroll")                                                            \
  for (int r = 0; r < 4; ++r) {                                                \
    gload_lds16(APTR(r, kt), Alds + t * 8 + 2048 * r);                         \
    gload_lds16(bsrc + (size_t)(kt) * BK + (size_t)(32 * r) * HDIM,            \
                Blds + t * 8 + 2048 * r);                                      \
  }

#define GEMM_COMPUTE()                                                         \
  _Pragma("unroll")                                                            \
  for (int ks = 0; ks < 2; ++ks) {                                             \
    int ch = ((ks * 4 + hi) ^ xo) * 8;                                         \
    bf16x8 af[4], bv[4];                                                       \
    _Pragma("unroll")                                                          \
    for (int m = 0; m < 4; ++m)                                                \
      af[m] = *(const bf16x8*)(Alds + (arow0 + m * 16) * BK + ch);             \
    _Pragma("unroll")                                                          \
    for (int n2 = 0; n2 < 4; ++n2)                                             \
      bv[n2] = *(const bf16x8*)(Blds + (brow0 + n2 * 16) * BK + ch);           \
    _Pragma("unroll")                                                          \
    for (int m = 0; m < 4; ++m)                                                \
      _Pragma("unroll")                                                        \
      for (int n2 = 0; n2 < 4; ++n2)                                           \
        acc[m][n2] = __builtin_amdgcn_mfma_f32_16x16x32_bf16(                  \
            af[m], bv[n2], acc[m][n2], 0, 0, 0);                               \
  }

#define GEMM_MAINLOOP()                                                        \
  for (int kt = 0; kt < NKT; ++kt) {                                           \
    __syncthreads();                                                           \
    GEMM_STAGE(kt);                                                            \
    __syncthreads();                                                           \
    GEMM_COMPUTE();                                                            \
  }

__global__ __launch_bounds__(256) void gemm1_kernel(
    const unsigned short* __restrict__ tokB,  // [N][H] token order
    const unsigned short* __restrict__ w1B,   // [E][H][H]
    const float* __restrict__ b1,             // [E][H]
    const int* __restrict__ counts,
    const int* __restrict__ tmeta,
    const int* __restrict__ topos,
    unsigned short* __restrict__ Hbuf)        // [N][H] compacted
{
  GEMM_PREAMBLE()
  int tokr[4];
#pragma unroll
  for (int r = 0; r < 4; ++r) {
    int pos = base + mt * BM + rowi + 32 * r;
    if (pos > N_TOK - 1) pos = N_TOK - 1;
    tokr[r] = topos[pos];
  }
  const unsigned short* bsrc =
      w1B + ((size_t)e << 20) + (size_t)(nt * BN + rowi) * HDIM + sch * 8;
#define APTR(r, kt) (tokB + (size_t)tokr[r] * HDIM + (kt) * BK + sch * 8)
  GEMM_MAINLOOP()
#undef APTR

  int crow0 = wr * 64 + (lane >> 4) * 4;
  int ccol0 = wc * 64 + (lane & 15);
  float bias[4];
#pragma unroll
  for (int n2 = 0; n2 < 4; ++n2)
    bias[n2] = b1[e * HDIM + nt * BN + ccol0 + n2 * 16];
#pragma unroll
  for (int m = 0; m < 4; ++m) {
#pragma unroll
    for (int j = 0; j < 4; ++j) {
      int row = crow0 + m * 16 + j;
      if (mt * BM + row < cnt) {
        size_t orow = (size_t)(base + mt * BM + row) * HDIM + nt * BN;
#pragma unroll
        for (int n2 = 0; n2 < 4; ++n2) {
          float v = acc[m][n2][j] + bias[n2];
          v = v > 0.f ? v : 0.f;
          Hbuf[orow + ccol0 + n2 * 16] = f2bf(v);
        }
      }
    }
  }
}

__global__ __launch_bounds__(256) void gemm2_kernel(
    const unsigned short* __restrict__ Hbuf,  // [N][H] compacted
    const unsigned short* __restrict__ w2B,   // [E][H][H]
    const float* __restrict__ b2,             // [E][H]
    const int* __restrict__ counts,
    const int* __restrict__ tmeta,
    const int* __restrict__ topos,
    float* __restrict__ out)                  // [N][H] token order
{
  GEMM_PREAMBLE()
  int arows[4];
#pragma unroll
  for (int r = 0; r < 4; ++r) {
    int pos = base + mt * BM + rowi + 32 * r;
    arows[r] = pos > N_TOK - 1 ? N_TOK - 1 : pos;
  }
  const unsigned short* bsrc =
      w2B + ((size_t)e << 20) + (size_t)(nt * BN + rowi) * HDIM + sch * 8;
#define APTR(r, kt) (Hbuf + (size_t)arows[r] * HDIM + (kt) * BK + sch * 8)
  GEMM_MAINLOOP()
#undef APTR

  int crow0 = wr * 64 + (lane >> 4) * 4;
  int ccol0 = wc * 64 + (lane & 15);
  float bias[4];
#pragma unroll
  for (int n2 = 0; n2 < 4; ++n2)
    bias[n2] = b2[e * HDIM + nt * BN + ccol0 + n2 * 16];
#pragma unroll
  for (int m = 0; m < 4; ++m) {
#pragma unroll
    for (int j = 0; j < 4; ++j) {
      int row = crow0 + m * 16 + j;
      if (mt * BM + row < cnt) {
        int tok = topos[base + mt * BM + row];
        size_t orow = (size_t)tok * HDIM + nt * BN;
#pragma unroll
        for (int n2 = 0; n2 < 4; ++n2)
          out[orow + ccol0 + n2 * 16] = acc[m][n2][j] + bias[n2];
      }
    }
  }
}

extern "C" void kernel_launch(void* const* d_in, const int* in_sizes, int n_in,
                              void* d_out, int out_size, void* d_ws, size_t ws_size,
                              hipStream_t stream) {
  (void)in_sizes; (void)n_in; (void)out_size; (void)ws_size;
  const float* tokens = (const float*)d_in[0];
  const float* gate_w = (const float*)d_in[1];
  const float* w1     = (const float*)d_in[2];
  const float* b1     = (const float*)d_in[3];
  const float* w2     = (const float*)d_in[4];
  const float* b2     = (const float*)d_in[5];
  float* out          = (float*)d_out;

  char* ws = (char*)d_ws;
  size_t o = 0;
  int* counts = (int*)(ws + o); o += 256;
  int* tmeta  = (int*)(ws + o); o += 1024;
  int* eid    = (int*)(ws + o); o += (size_t)N_TOK * 4;
  int* rank   = (int*)(ws + o); o += (size_t)N_TOK * 4;
  int* topos  = (int*)(ws + o); o += (size_t)N_TOK * 4;
  unsigned short* tokB = (unsigned short*)(ws + o); o += (size_t)N_TOK * HDIM * 2;
  unsigned short* w1B  = (unsigned short*)(ws + o); o += (size_t)NE * HDIM * HDIM * 2;
  unsigned short* w2B  = (unsigned short*)(ws + o); o += (size_t)NE * HDIM * HDIM * 2;
  unsigned short* Hbuf = (unsigned short*)(ws + o); o += (size_t)N_TOK * HDIM * 2;

  gate_kernel<<<4096 + 1024, 256, 0, stream>>>(tokens, gate_w, w1, w2,
                                               tokB, w1B, w2B, eid, counts);
  rank_kernel<<<N_TOK / 256, 256, 0, stream>>>(eid, rank, counts);
  perm_kernel<<<N_TOK / 256, 256, 0, stream>>>(counts, eid, rank, topos, tmeta);
  gemm1_kernel<<<GRID_GEMM, 256, 0, stream>>>(tokB, w1B, b1, counts, tmeta, topos, Hbuf);
  gemm2_kernel<<<GRID_GEMM, 256, 0, stream>>>(Hbuf, w2B, b2, counts, tmeta, topos, out);
}

// Round 19
// 157.653 us; speedup vs baseline: 1.0426x; 1.0426x over previous
//
#include <hip/hip_runtime.h>
#include <hip/hip_bf16.h>
#include <stdint.h>

#define N_TOK 16384
#define HDIM  1024
#define NE    8

#define BM 128
#define BN 128
#define BK 64
#define NKT (HDIM / BK)            // 16
#define NT_N (HDIM / BN)           // 8
#define MAXTILES (N_TOK / BM + NE) // 136 worst-case row-tiles (136 % 8 == 0)
#define GRID_GEMM (MAXTILES * NT_N) // 1088

typedef __attribute__((ext_vector_type(8))) short          bf16x8;
typedef __attribute__((ext_vector_type(8))) unsigned short ushort8;
typedef __attribute__((ext_vector_type(4))) unsigned short ushort4v;
typedef __attribute__((ext_vector_type(4))) float          f32x4;

__device__ __forceinline__ unsigned short f2bf(float f) {
  union { float f; uint32_t u; } c; c.f = f;
  uint32_t u = c.u;
  uint32_t r = (u + 0x7fffu + ((u >> 16) & 1u)) >> 16;
  return (unsigned short)r;
}

__device__ __forceinline__ void gload_lds16(const void* g, void* l) {
  __builtin_amdgcn_global_load_lds((const __attribute__((address_space(1))) void*)g,
                                   (__attribute__((address_space(3))) void*)l, 16, 0, 0);
}

__device__ __forceinline__ void expert_range(const int* __restrict__ counts, int e,
                                             int& base, int& cnt) {
  int run = 0; base = 0; cnt = 0;
#pragma unroll
  for (int i = 0; i < NE; ++i) {
    int c = counts[i];
    if (i == e) { base = run; cnt = c; }
    run += c;
  }
}

// ---------------------------------------------------------------------------
// Fused gate + weight-cvt, 512 threads / 8 tokens per block (2048 blocks):
// gate_w staged once per block (half the total stage traffic of r16's
// 4-token blocks) and 512-thread blocks raise resident waves per CU
// (LDS 32KB still allows multiple blocks) to hide the per-block latency
// chain that capped r15-r18 at ~57us. Weight slice = 8192 f32/block.
// counts zeroed by block 0.
// ---------------------------------------------------------------------------
__global__ __launch_bounds__(512) void gate_kernel(
    const float* __restrict__ tokens, const float* __restrict__ gate_w,
    const float* __restrict__ w1f, const float* __restrict__ w2f,
    unsigned short* __restrict__ tokB, unsigned short* __restrict__ w1B,
    unsigned short* __restrict__ w2B, int* __restrict__ eid,
    int* __restrict__ counts)
{
  __shared__ float gw[NE * HDIM];  // 32 KB

  int t = threadIdx.x;
  if (blockIdx.x == 0 && t < NE) counts[t] = 0;

  // stage gate_w -> LDS once (4 x 16B per thread, async DMA)
#pragma unroll
  for (int h = 0; h < 4; ++h) {
    size_t f = (size_t)h * 2048 + (size_t)t * 4;
    gload_lds16(gate_w + f, gw + f);
  }

  // weight slice: issue the 4 float4 loads early (held in regs)
  int b = blockIdx.x;
  const float* wsrc = (b < 1024) ? w1f : w2f;
  unsigned short* wdst = (b < 1024) ? w1B : w2B;
  size_t wi0 = ((size_t)(b & 1023) * 8192) + (size_t)t * 16;
  float4 wf[4];
#pragma unroll
  for (int h = 0; h < 4; ++h)
    wf[h] = *(const float4*)(wsrc + wi0 + h * 4);

  // token loads + bf16 store (one token per wave; 8 waves)
  int wid  = t >> 6;
  int lane = t & 63;
  int n    = blockIdx.x * 8 + wid;

  const float* trow = tokens + (size_t)n * HDIM;
  float4 x[4];
#pragma unroll
  for (int i = 0; i < 4; ++i)
    x[i] = *(const float4*)(trow + i * 256 + lane * 4);

  unsigned short* drow = tokB + (size_t)n * HDIM;
#pragma unroll
  for (int i = 0; i < 4; ++i) {
    ushort4v o;
    o[0] = f2bf(x[i].x); o[1] = f2bf(x[i].y);
    o[2] = f2bf(x[i].z); o[3] = f2bf(x[i].w);
    *(ushort4v*)(drow + i * 256 + lane * 4) = o;
  }

  __syncthreads();  // gate_w staged (drains all outstanding loads)

  // gate math from LDS (f64 accum)
  double acc[NE];
#pragma unroll
  for (int e = 0; e < NE; ++e) {
    const float* grow = gw + e * HDIM;
    double a = 0.0;
#pragma unroll
    for (int i = 0; i < 4; ++i) {
      float4 g = *(const float4*)(grow + i * 256 + lane * 4);
      a += (double)x[i].x * g.x + (double)x[i].y * g.y
         + (double)x[i].z * g.z + (double)x[i].w * g.w;
    }
    acc[e] = a;
  }
#pragma unroll
  for (int off = 32; off; off >>= 1) {
#pragma unroll
    for (int e = 0; e < NE; ++e) acc[e] += __shfl_xor(acc[e], off);
  }
  if (lane == 0) {
    int best = 0; double bv = acc[0];
#pragma unroll
    for (int e = 1; e < NE; ++e) if (acc[e] > bv) { bv = acc[e]; best = e; }
    eid[n] = best;
  }

  // weight slice: convert + store
  {
    ushort8 o0, o1;
    o0[0] = f2bf(wf[0].x); o0[1] = f2bf(wf[0].y); o0[2] = f2bf(wf[0].z); o0[3] = f2bf(wf[0].w);
    o0[4] = f2bf(wf[1].x); o0[5] = f2bf(wf[1].y); o0[6] = f2bf(wf[1].z); o0[7] = f2bf(wf[1].w);
    o1[0] = f2bf(wf[2].x); o1[1] = f2bf(wf[2].y); o1[2] = f2bf(wf[2].z); o1[3] = f2bf(wf[2].w);
    o1[4] = f2bf(wf[3].x); o1[5] = f2bf(wf[3].y); o1[6] = f2bf(wf[3].z); o1[7] = f2bf(wf[3].w);
    *(ushort8*)(wdst + wi0)     = o0;
    *(ushort8*)(wdst + wi0 + 8) = o1;
  }
}

// ---------------------------------------------------------------------------
// Rank: LDS histogram per 256-token block; 8 global atomics per block.
// ---------------------------------------------------------------------------
__global__ __launch_bounds__(256) void rank_kernel(
    const int* __restrict__ eid, int* __restrict__ rank, int* __restrict__ counts)
{
  __shared__ int h[NE];
  __shared__ int bbase[NE];
  int t = threadIdx.x;
  int n = blockIdx.x * 256 + t;
  if (t < NE) h[t] = 0;
  __syncthreads();
  int e = eid[n];
  int r = atomicAdd(&h[e], 1);
  __syncthreads();
  if (t < NE) bbase[t] = atomicAdd(&counts[t], h[t]);
  __syncthreads();
  rank[n] = bbase[e] + r;
}

// perm + tilemap fused (r11-verified): scatter token index; block 0 thread 0
// also emits the compact active-tile list for the GEMM grid.
__global__ __launch_bounds__(256) void perm_kernel(
    const int* __restrict__ counts, const int* __restrict__ eid,
    const int* __restrict__ rank, int* __restrict__ topos,
    int* __restrict__ tmeta)
{
  __shared__ int off[NE];
  int t = threadIdx.x;
  if (t == 0) {
    int run = 0;
#pragma unroll
    for (int e = 0; e < NE; ++e) { off[e] = run; run += counts[e]; }
  }
  __syncthreads();
  int n = blockIdx.x * 256 + t;
  topos[off[eid[n]] + rank[n]] = n;
  if (blockIdx.x == 0 && t == 0) {
    int idx = 0;
    for (int e = 0; e < NE; ++e) {
      int ntile = (counts[e] + BM - 1) / BM;
      for (int mt = 0; mt < ntile; ++mt) tmeta[1 + idx++] = (mt << 3) | e;
    }
    tmeta[0] = idx;
  }
}

// ---------------------------------------------------------------------------
// Grouped GEMM, r5-verified m97 structure: 128x128 tile, BK=64, 4 waves (2x2),
// single 32KB LDS buffer, 2 syncthreads per K-tile, compiler-scheduled waits.
// Both-sides chunk-XOR LDS swizzle (0 conflicts). XCD-chunked block swizzle
// (17 consecutive tiles ~ one expert per XCD; FETCH 141->36 MB).
// ---------------------------------------------------------------------------
#define GEMM_PREAMBLE()                                                        \
  int bid = blockIdx.x;                                                        \
  int logical = (bid & 7) * (GRID_GEMM / 8) + (bid >> 3);                      \
  int tile = logical >> 3;                                                     \
  int nt   = logical & 7;                                                      \
  if (tile >= tmeta[0]) return;                                                \
  int ent = tmeta[1 + tile];                                                   \
  int e = ent & 7, mt = ent >> 3;                                              \
  int base, cnt;                                                               \
  expert_range(counts, e, base, cnt);                                          \
  __shared__ unsigned short Alds[BM * BK];                                     \
  __shared__ unsigned short Blds[BN * BK];                                     \
  int t    = threadIdx.x;                                                      \
  int kc   = t & 7;            /* 16B chunk within row */                      \
  int rowi = t >> 3;           /* 0..31 */                                     \
  int sch  = kc ^ (rowi & 7);  /* inverse-swizzled source chunk */             \
  int lane = t & 63, wid = t >> 6;                                             \
  int wr = wid >> 1, wc = wid & 1;                                             \
  f32x4 acc[4][4] = {};                                                        \
  int arow0 = wr * 64 + (lane & 15);                                           \
  int brow0 = wc * 64 + (lane & 15);                                           \
  int hi    = lane >> 4;       /* 0..3 */                                      \
  int xo    = lane & 7;        /* read-side XOR */

#define GEMM_STAGE(kt)                                                         \
  _Pragma("unroll")                                                            \
  for (int r = 0; r < 4; ++r) {                                                \
    gload_lds16(APTR(r, kt), Alds + t * 8 + 2048 * r);                         \
    gload_lds16(bsrc + (size_t)(kt) * BK + (size_t)(32 * r) * HDIM,            \
                Blds + t * 8 + 2048 * r);                                      \
  }

#define GEMM_COMPUTE()                                                         \
  _Pragma("unroll")                                                            \
  for (int ks = 0; ks < 2; ++ks) {                                             \
    int ch = ((ks * 4 + hi) ^ xo) * 8;                                         \
    bf16x8 af[4], bv[4];                                                       \
    _Pragma("unroll")                                                          \
    for (int m = 0; m < 4; ++m)                                                \
      af[m] = *(const bf16x8*)(Alds + (arow0 + m * 16) * BK + ch);             \
    _Pragma("unroll")                                                          \
    for (int n2 = 0; n2 < 4; ++n2)                                             \
      bv[n2] = *(const bf16x8*)(Blds + (brow0 + n2 * 16) * BK + ch);           \
    _Pragma("unroll")                                                          \
    for (int m = 0; m < 4; ++m)                                                \
      _Pragma("unroll")                                                        \
      for (int n2 = 0; n2 < 4; ++n2)                                           \
        acc[m][n2] = __builtin_amdgcn_mfma_f32_16x16x32_bf16(                  \
            af[m], bv[n2], acc[m][n2], 0, 0, 0);                               \
  }

#define GEMM_MAINLOOP()                                                        \
  for (int kt = 0; kt < NKT; ++kt) {                                           \
    __syncthreads();                                                           \
    GEMM_STAGE(kt);                                                            \
    __syncthreads();                                                           \
    GEMM_COMPUTE();                                                            \
  }

__global__ __launch_bounds__(256) void gemm1_kernel(
    const unsigned short* __restrict__ tokB,  // [N][H] token order
    const unsigned short* __restrict__ w1B,   // [E][H][H]
    const float* __restrict__ b1,             // [E][H]
    const int* __restrict__ counts,
    const int* __restrict__ tmeta,
    const int* __restrict__ topos,
    unsigned short* __restrict__ Hbuf)        // [N][H] compacted
{
  GEMM_PREAMBLE()
  int tokr[4];
#pragma unroll
  for (int r = 0; r < 4; ++r) {
    int pos = base + mt * BM + rowi + 32 * r;
    if (pos > N_TOK - 1) pos = N_TOK - 1;
    tokr[r] = topos[pos];
  }
  const unsigned short* bsrc =
      w1B + ((size_t)e << 20) + (size_t)(nt * BN + rowi) * HDIM + sch * 8;
#define APTR(r, kt) (tokB + (size_t)tokr[r] * HDIM + (kt) * BK + sch * 8)
  GEMM_MAINLOOP()
#undef APTR

  int crow0 = wr * 64 + (lane >> 4) * 4;
  int ccol0 = wc * 64 + (lane & 15);
  float bias[4];
#pragma unroll
  for (int n2 = 0; n2 < 4; ++n2)
    bias[n2] = b1[e * HDIM + nt * BN + ccol0 + n2 * 16];
#pragma unroll
  for (int m = 0; m < 4; ++m) {
#pragma unroll
    for (int j = 0; j < 4; ++j) {
      int row = crow0 + m * 16 + j;
      if (mt * BM + row < cnt) {
        size_t orow = (size_t)(base + mt * BM + row) * HDIM + nt * BN;
#pragma unroll
        for (int n2 = 0; n2 < 4; ++n2) {
          float v = acc[m][n2][j] + bias[n2];
          v = v > 0.f ? v : 0.f;
          Hbuf[orow + ccol0 + n2 * 16] = f2bf(v);
        }
      }
    }
  }
}

__global__ __launch_bounds__(256) void gemm2_kernel(
    const unsigned short* __restrict__ Hbuf,  // [N][H] compacted
    const unsigned short* __restrict__ w2B,   // [E][H][H]
    const float* __restrict__ b2,             // [E][H]
    const int* __restrict__ counts,
    const int* __restrict__ tmeta,
    const int* __restrict__ topos,
    float* __restrict__ out)                  // [N][H] token order
{
  GEMM_PREAMBLE()
  int arows[4];
#pragma unroll
  for (int r = 0; r < 4; ++r) {
    int pos = base + mt * BM + rowi + 32 * r;
    arows[r] = pos > N_TOK - 1 ? N_TOK - 1 : pos;
  }
  const unsigned short* bsrc =
      w2B + ((size_t)e << 20) + (size_t)(nt * BN + rowi) * HDIM + sch * 8;
#define APTR(r, kt) (Hbuf + (size_t)arows[r] * HDIM + (kt) * BK + sch * 8)
  GEMM_MAINLOOP()
#undef APTR

  int crow0 = wr * 64 + (lane >> 4) * 4;
  int ccol0 = wc * 64 + (lane & 15);
  float bias[4];
#pragma unroll
  for (int n2 = 0; n2 < 4; ++n2)
    bias[n2] = b2[e * HDIM + nt * BN + ccol0 + n2 * 16];
#pragma unroll
  for (int m = 0; m < 4; ++m) {
#pragma unroll
    for (int j = 0; j < 4; ++j) {
      int row = crow0 + m * 16 + j;
      if (mt * BM + row < cnt) {
        int tok = topos[base + mt * BM + row];
        size_t orow = (size_t)tok * HDIM + nt * BN;
#pragma unroll
        for (int n2 = 0; n2 < 4; ++n2)
          out[orow + ccol0 + n2 * 16] = acc[m][n2][j] + bias[n2];
      }
    }
  }
}

extern "C" void kernel_launch(void* const* d_in, const int* in_sizes, int n_in,
                              void* d_out, int out_size, void* d_ws, size_t ws_size,
                              hipStream_t stream) {
  (void)in_sizes; (void)n_in; (void)out_size; (void)ws_size;
  const float* tokens = (const float*)d_in[0];
  const float* gate_w = (const float*)d_in[1];
  const float* w1     = (const float*)d_in[2];
  const float* b1     = (const float*)d_in[3];
  const float* w2     = (const float*)d_in[4];
  const float* b2     = (const float*)d_in[5];
  float* out          = (float*)d_out;

  char* ws = (char*)d_ws;
  size_t o = 0;
  int* counts = (int*)(ws + o); o += 256;
  int* tmeta  = (int*)(ws + o); o += 1024;
  int* eid    = (int*)(ws + o); o += (size_t)N_TOK * 4;
  int* rank   = (int*)(ws + o); o += (size_t)N_TOK * 4;
  int* topos  = (int*)(ws + o); o += (size_t)N_TOK * 4;
  unsigned short* tokB = (unsigned short*)(ws + o); o += (size_t)N_TOK * HDIM * 2;
  unsigned short* w1B  = (unsigned short*)(ws + o); o += (size_t)NE * HDIM * HDIM * 2;
  unsigned short* w2B  = (unsigned short*)(ws + o); o += (size_t)NE * HDIM * HDIM * 2;
  unsigned short* Hbuf = (unsigned short*)(ws + o); o += (size_t)N_TOK * HDIM * 2;

  gate_kernel<<<N_TOK / 8, 512, 0, stream>>>(tokens, gate_w, w1, w2,
                                             tokB, w1B, w2B, eid, counts);
  rank_kernel<<<N_TOK / 256, 256, 0, stream>>>(eid, rank, counts);
  perm_kernel<<<N_TOK / 256, 256, 0, stream>>>(counts, eid, rank, topos, tmeta);
  gemm1_kernel<<<GRID_GEMM, 256, 0, stream>>>(tokB, w1B, b1, counts, tmeta, topos, Hbuf);
  gemm2_kernel<<<GRID_GEMM, 256, 0, stream>>>(Hbuf, w2B, b2, counts, tmeta, topos, out);
}

// Round 20
// 153.308 us; speedup vs baseline: 1.0721x; 1.0283x over previous
//
#include <hip/hip_runtime.h>
#include <hip/hip_bf16.h>
#include <stdint.h>

#define N_TOK 16384
#define HDIM  1024
#define NE    8

#define BM 128
#define BN 128
#define BK 64
#define NKT (HDIM / BK)            // 16
#define NT_N (HDIM / BN)           // 8
#define MAXTILES (N_TOK / BM + NE) // 136 worst-case row-tiles (136 % 8 == 0)
#define GRID_GEMM (MAXTILES * NT_N) // 1088

typedef __attribute__((ext_vector_type(8))) short          bf16x8;
typedef __attribute__((ext_vector_type(8))) unsigned short ushort8;
typedef __attribute__((ext_vector_type(4))) unsigned short ushort4v;
typedef __attribute__((ext_vector_type(4))) float          f32x4;

__device__ __forceinline__ unsigned short f2bf(float f) {
  union { float f; uint32_t u; } c; c.f = f;
  uint32_t u = c.u;
  uint32_t r = (u + 0x7fffu + ((u >> 16) & 1u)) >> 16;
  return (unsigned short)r;
}

__device__ __forceinline__ void gload_lds16(const void* g, void* l) {
  __builtin_amdgcn_global_load_lds((const __attribute__((address_space(1))) void*)g,
                                   (__attribute__((address_space(3))) void*)l, 16, 0, 0);
}

__device__ __forceinline__ void expert_range(const int* __restrict__ counts, int e,
                                             int& base, int& cnt) {
  int run = 0; base = 0; cnt = 0;
#pragma unroll
  for (int i = 0; i < NE; ++i) {
    int c = counts[i];
    if (i == e) { base = run; cnt = c; }
    run += c;
  }
}

// ---------------------------------------------------------------------------
// Fused gate + weight-cvt (r16 structure, best measured) with gate math in
// F32: logit gaps (>=~1e-5, proven by the f32 reference's stable routing)
// dwarf f32 accumulation error (~1-3e-6); f64->f32 halves the dependent
// FMA-chain latency and the shuffle-reduce word count — the measured
// latency bottleneck (r19: occupancy 51% yet still 61us => chain-bound).
// gate_w staged once to LDS; weight slice converted per block; counts
// zeroed by block 0.
// ---------------------------------------------------------------------------
__global__ __launch_bounds__(256) void gate_kernel(
    const float* __restrict__ tokens, const float* __restrict__ gate_w,
    const float* __restrict__ w1f, const float* __restrict__ w2f,
    unsigned short* __restrict__ tokB, unsigned short* __restrict__ w1B,
    unsigned short* __restrict__ w2B, int* __restrict__ eid,
    int* __restrict__ counts)
{
  __shared__ float gw[NE * HDIM];  // 32 KB

  int t = threadIdx.x;
  if (blockIdx.x == 0 && t < NE) counts[t] = 0;

  // stage gate_w -> LDS once (8 x 16B per thread, async DMA)
#pragma unroll
  for (int h = 0; h < 8; ++h) {
    size_t f = (size_t)h * 1024 + (size_t)t * 4;
    gload_lds16(gate_w + f, gw + f);
  }

  // weight slice: issue loads, hold in registers
  int b = blockIdx.x;
  const float* wsrc = (b < 2048) ? w1f : w2f;
  unsigned short* wdst = (b < 2048) ? w1B : w2B;
  size_t wi0 = ((size_t)(b & 2047) * 4096) + (size_t)t * 16;
  float4 wf[4];
#pragma unroll
  for (int h = 0; h < 4; ++h)
    wf[h] = *(const float4*)(wsrc + wi0 + h * 4);

  // token loads + bf16 store
  int wid  = t >> 6;
  int lane = t & 63;
  int n    = blockIdx.x * 4 + wid;

  const float* trow = tokens + (size_t)n * HDIM;
  float4 x[4];
#pragma unroll
  for (int i = 0; i < 4; ++i)
    x[i] = *(const float4*)(trow + i * 256 + lane * 4);

  unsigned short* drow = tokB + (size_t)n * HDIM;
#pragma unroll
  for (int i = 0; i < 4; ++i) {
    ushort4v o;
    o[0] = f2bf(x[i].x); o[1] = f2bf(x[i].y);
    o[2] = f2bf(x[i].z); o[3] = f2bf(x[i].w);
    *(ushort4v*)(drow + i * 256 + lane * 4) = o;
  }

  __syncthreads();  // gate_w staged (drains all outstanding loads)

  // gate math from LDS (f32 accum)
  float acc[NE];
#pragma unroll
  for (int e = 0; e < NE; ++e) {
    const float* grow = gw + e * HDIM;
    float a = 0.f;
#pragma unroll
    for (int i = 0; i < 4; ++i) {
      float4 g = *(const float4*)(grow + i * 256 + lane * 4);
      a += x[i].x * g.x + x[i].y * g.y + x[i].z * g.z + x[i].w * g.w;
    }
    acc[e] = a;
  }
#pragma unroll
  for (int off = 32; off; off >>= 1) {
#pragma unroll
    for (int e = 0; e < NE; ++e) acc[e] += __shfl_xor(acc[e], off);
  }
  if (lane == 0) {
    int best = 0; float bv = acc[0];
#pragma unroll
    for (int e = 1; e < NE; ++e) if (acc[e] > bv) { bv = acc[e]; best = e; }
    eid[n] = best;
  }

  // weight slice: convert + store
  {
    ushort8 o0, o1;
    o0[0] = f2bf(wf[0].x); o0[1] = f2bf(wf[0].y); o0[2] = f2bf(wf[0].z); o0[3] = f2bf(wf[0].w);
    o0[4] = f2bf(wf[1].x); o0[5] = f2bf(wf[1].y); o0[6] = f2bf(wf[1].z); o0[7] = f2bf(wf[1].w);
    o1[0] = f2bf(wf[2].x); o1[1] = f2bf(wf[2].y); o1[2] = f2bf(wf[2].z); o1[3] = f2bf(wf[2].w);
    o1[4] = f2bf(wf[3].x); o1[5] = f2bf(wf[3].y); o1[6] = f2bf(wf[3].z); o1[7] = f2bf(wf[3].w);
    *(ushort8*)(wdst + wi0)     = o0;
    *(ushort8*)(wdst + wi0 + 8) = o1;
  }
}

// ---------------------------------------------------------------------------
// Rank: LDS histogram per 256-token block; 8 global atomics per block.
// ---------------------------------------------------------------------------
__global__ __launch_bounds__(256) void rank_kernel(
    const int* __restrict__ eid, int* __restrict__ rank, int* __restrict__ counts)
{
  __shared__ int h[NE];
  __shared__ int bbase[NE];
  int t = threadIdx.x;
  int n = blockIdx.x * 256 + t;
  if (t < NE) h[t] = 0;
  __syncthreads();
  int e = eid[n];
  int r = atomicAdd(&h[e], 1);
  __syncthreads();
  if (t < NE) bbase[t] = atomicAdd(&counts[t], h[t]);
  __syncthreads();
  rank[n] = bbase[e] + r;
}

// perm + tilemap fused (r11-verified): scatter token index; block 0 thread 0
// also emits the compact active-tile list for the GEMM grid.
__global__ __launch_bounds__(256) void perm_kernel(
    const int* __restrict__ counts, const int* __restrict__ eid,
    const int* __restrict__ rank, int* __restrict__ topos,
    int* __restrict__ tmeta)
{
  __shared__ int off[NE];
  int t = threadIdx.x;
  if (t == 0) {
    int run = 0;
#pragma unroll
    for (int e = 0; e < NE; ++e) { off[e] = run; run += counts[e]; }
  }
  __syncthreads();
  int n = blockIdx.x * 256 + t;
  topos[off[eid[n]] + rank[n]] = n;
  if (blockIdx.x == 0 && t == 0) {
    int idx = 0;
    for (int e = 0; e < NE; ++e) {
      int ntile = (counts[e] + BM - 1) / BM;
      for (int mt = 0; mt < ntile; ++mt) tmeta[1 + idx++] = (mt << 3) | e;
    }
    tmeta[0] = idx;
  }
}

// ---------------------------------------------------------------------------
// Grouped GEMM, r5-verified m97 structure: 128x128 tile, BK=64, 4 waves (2x2),
// single 32KB LDS buffer, 2 syncthreads per K-tile, compiler-scheduled waits.
// Both-sides chunk-XOR LDS swizzle (0 conflicts). XCD-chunked block swizzle
// (17 consecutive tiles ~ one expert per XCD; FETCH 141->36 MB).
// ---------------------------------------------------------------------------
#define GEMM_PREAMBLE()                                                        \
  int bid = blockIdx.x;                                                        \
  int logical = (bid & 7) * (GRID_GEMM / 8) + (bid >> 3);                      \
  int tile = logical >> 3;                                                     \
  int nt   = logical & 7;                                                      \
  if (tile >= tmeta[0]) return;                                                \
  int ent = tmeta[1 + tile];                                                   \
  int e = ent & 7, mt = ent >> 3;                                              \
  int base, cnt;                                                               \
  expert_range(counts, e, base, cnt);                                          \
  __shared__ unsigned short Alds[BM * BK];                                     \
  __shared__ unsigned short Blds[BN * BK];                                     \
  int t    = threadIdx.x;                                                      \
  int kc   = t & 7;            /* 16B chunk within row */                      \
  int rowi = t >> 3;           /* 0..31 */                                     \
  int sch  = kc ^ (rowi & 7);  /* inverse-swizzled source chunk */             \
  int lane = t & 63, wid = t >> 6;                                             \
  int wr = wid >> 1, wc = wid & 1;                                             \
  f32x4 acc[4][4] = {};                                                        \
  int arow0 = wr * 64 + (lane & 15);                                           \
  int brow0 = wc * 64 + (lane & 15);                                           \
  int hi    = lane >> 4;       /* 0..3 */                                      \
  int xo    = lane & 7;        /* read-side XOR */

#define GEMM_STAGE(kt)                                                         \
  _Pragma("unroll")                                                            \
  for (int r = 0; r < 4; ++r) {                                                \
    gload_lds16(APTR(r, kt), Alds + t * 8 + 2048 * r);                         \
    gload_lds16(bsrc + (size_t)(kt) * BK + (size_t)(32 * r) * HDIM,            \
                Blds + t * 8 + 2048 * r);                                      \
  }

#define GEMM_COMPUTE()                                                         \
  _Pragma("unroll")                                                            \
  for (int ks = 0; ks < 2; ++ks) {                                             \
    int ch = ((ks * 4 + hi) ^ xo) * 8;                                         \
    bf16x8 af[4], bv[4];                                                       \
    _Pragma("unroll")                                                          \
    for (int m = 0; m < 4; ++m)                                                \
      af[m] = *(const bf16x8*)(Alds + (arow0 + m * 16) * BK + ch);             \
    _Pragma("unroll")                                                          \
    for (int n2 = 0; n2 < 4; ++n2)                                             \
      bv[n2] = *(const bf16x8*)(Blds + (brow0 + n2 * 16) * BK + ch);           \
    _Pragma("unroll")                                                          \
    for (int m = 0; m < 4; ++m)                                                \
      _Pragma("unroll")                                                        \
      for (int n2 = 0; n2 < 4; ++n2)                                           \
        acc[m][n2] = __builtin_amdgcn_mfma_f32_16x16x32_bf16(                  \
            af[m], bv[n2], acc[m][n2], 0, 0, 0);                               \
  }

#define GEMM_MAINLOOP()                                                        \
  for (int kt = 0; kt < NKT; ++kt) {                                           \
    __syncthreads();                                                           \
    GEMM_STAGE(kt);                                                            \
    __syncthreads();                                                           \
    GEMM_COMPUTE();                                                            \
  }

__global__ __launch_bounds__(256) void gemm1_kernel(
    const unsigned short* __restrict__ tokB,  // [N][H] token order
    const unsigned short* __restrict__ w1B,   // [E][H][H]
    const float* __restrict__ b1,             // [E][H]
    const int* __restrict__ counts,
    const int* __restrict__ tmeta,
    const int* __restrict__ topos,
    unsigned short* __restrict__ Hbuf)        // [N][H] compacted
{
  GEMM_PREAMBLE()
  int tokr[4];
#pragma unroll
  for (int r = 0; r < 4; ++r) {
    int pos = base + mt * BM + rowi + 32 * r;
    if (pos > N_TOK - 1) pos = N_TOK - 1;
    tokr[r] = topos[pos];
  }
  const unsigned short* bsrc =
      w1B + ((size_t)e << 20) + (size_t)(nt * BN + rowi) * HDIM + sch * 8;
#define APTR(r, kt) (tokB + (size_t)tokr[r] * HDIM + (kt) * BK + sch * 8)
  GEMM_MAINLOOP()
#undef APTR

  int crow0 = wr * 64 + (lane >> 4) * 4;
  int ccol0 = wc * 64 + (lane & 15);
  float bias[4];
#pragma unroll
  for (int n2 = 0; n2 < 4; ++n2)
    bias[n2] = b1[e * HDIM + nt * BN + ccol0 + n2 * 16];
#pragma unroll
  for (int m = 0; m < 4; ++m) {
#pragma unroll
    for (int j = 0; j < 4; ++j) {
      int row = crow0 + m * 16 + j;
      if (mt * BM + row < cnt) {
        size_t orow = (size_t)(base + mt * BM + row) * HDIM + nt * BN;
#pragma unroll
        for (int n2 = 0; n2 < 4; ++n2) {
          float v = acc[m][n2][j] + bias[n2];
          v = v > 0.f ? v : 0.f;
          Hbuf[orow + ccol0 + n2 * 16] = f2bf(v);
        }
      }
    }
  }
}

__global__ __launch_bounds__(256) void gemm2_kernel(
    const unsigned short* __restrict__ Hbuf,  // [N][H] compacted
    const unsigned short* __restrict__ w2B,   // [E][H][H]
    const float* __restrict__ b2,             // [E][H]
    const int* __restrict__ counts,
    const int* __restrict__ tmeta,
    const int* __restrict__ topos,
    float* __restrict__ out)                  // [N][H] token order
{
  GEMM_PREAMBLE()
  int arows[4];
#pragma unroll
  for (int r = 0; r < 4; ++r) {
    int pos = base + mt * BM + rowi + 32 * r;
    arows[r] = pos > N_TOK - 1 ? N_TOK - 1 : pos;
  }
  const unsigned short* bsrc =
      w2B + ((size_t)e << 20) + (size_t)(nt * BN + rowi) * HDIM + sch * 8;
#define APTR(r, kt) (Hbuf + (size_t)arows[r] * HDIM + (kt) * BK + sch * 8)
  GEMM_MAINLOOP()
#undef APTR

  int crow0 = wr * 64 + (lane >> 4) * 4;
  int ccol0 = wc * 64 + (lane & 15);
  float bias[4];
#pragma unroll
  for (int n2 = 0; n2 < 4; ++n2)
    bias[n2] = b2[e * HDIM + nt * BN + ccol0 + n2 * 16];
#pragma unroll
  for (int m = 0; m < 4; ++m) {
#pragma unroll
    for (int j = 0; j < 4; ++j) {
      int row = crow0 + m * 16 + j;
      if (mt * BM + row < cnt) {
        int tok = topos[base + mt * BM + row];
        size_t orow = (size_t)tok * HDIM + nt * BN;
#pragma unroll
        for (int n2 = 0; n2 < 4; ++n2)
          out[orow + ccol0 + n2 * 16] = acc[m][n2][j] + bias[n2];
      }
    }
  }
}

extern "C" void kernel_launch(void* const* d_in, const int* in_sizes, int n_in,
                              void* d_out, int out_size, void* d_ws, size_t ws_size,
                              hipStream_t stream) {
  (void)in_sizes; (void)n_in; (void)out_size; (void)ws_size;
  const float* tokens = (const float*)d_in[0];
  const float* gate_w = (const float*)d_in[1];
  const float* w1     = (const float*)d_in[2];
  const float* b1     = (const float*)d_in[3];
  const float* w2     = (const float*)d_in[4];
  const float* b2     = (const float*)d_in[5];
  float* out          = (float*)d_out;

  char* ws = (char*)d_ws;
  size_t o = 0;
  int* counts = (int*)(ws + o); o += 256;
  int* tmeta  = (int*)(ws + o); o += 1024;
  int* eid    = (int*)(ws + o); o += (size_t)N_TOK * 4;
  int* rank   = (int*)(ws + o); o += (size_t)N_TOK * 4;
  int* topos  = (int*)(ws + o); o += (size_t)N_TOK * 4;
  unsigned short* tokB = (unsigned short*)(ws + o); o += (size_t)N_TOK * HDIM * 2;
  unsigned short* w1B  = (unsigned short*)(ws + o); o += (size_t)NE * HDIM * HDIM * 2;
  unsigned short* w2B  = (unsigned short*)(ws + o); o += (size_t)NE * HDIM * HDIM * 2;
  unsigned short* Hbuf = (unsigned short*)(ws + o); o += (size_t)N_TOK * HDIM * 2;

  gate_kernel<<<N_TOK / 4, 256, 0, stream>>>(tokens, gate_w, w1, w2,
                                             tokB, w1B, w2B, eid, counts);
  rank_kernel<<<N_TOK / 256, 256, 0, stream>>>(eid, rank, counts);
  perm_kernel<<<N_TOK / 256, 256, 0, stream>>>(counts, eid, rank, topos, tmeta);
  gemm1_kernel<<<GRID_GEMM, 256, 0, stream>>>(tokB, w1B, b1, counts, tmeta, topos, Hbuf);
  gemm2_kernel<<<GRID_GEMM, 256, 0, stream>>>(Hbuf, w2B, b2, counts, tmeta, topos, out);
}

// Round 21
// 152.143 us; speedup vs baseline: 1.0803x; 1.0077x over previous
//
#include <hip/hip_runtime.h>
#include <hip/hip_bf16.h>
#include <stdint.h>

#define N_TOK 16384
#define HDIM  1024
#define NE    8

#define BM 128
#define BN 128
#define BK 64
#define NKT (HDIM / BK)            // 16
#define NT_N (HDIM / BN)           // 8
#define MAXTILES (N_TOK / BM + NE) // 136 worst-case row-tiles (136 % 8 == 0)
#define GRID_GEMM (MAXTILES * NT_N) // 1088

typedef __attribute__((ext_vector_type(8))) short          bf16x8;
typedef __attribute__((ext_vector_type(8))) unsigned short ushort8;
typedef __attribute__((ext_vector_type(4))) unsigned short ushort4v;
typedef __attribute__((ext_vector_type(4))) float          f32x4;

__device__ __forceinline__ unsigned short f2bf(float f) {
  union { float f; uint32_t u; } c; c.f = f;
  uint32_t u = c.u;
  uint32_t r = (u + 0x7fffu + ((u >> 16) & 1u)) >> 16;
  return (unsigned short)r;
}

__device__ __forceinline__ void gload_lds16(const void* g, void* l) {
  __builtin_amdgcn_global_load_lds((const __attribute__((address_space(1))) void*)g,
                                   (__attribute__((address_space(3))) void*)l, 16, 0, 0);
}

__device__ __forceinline__ void expert_range(const int* __restrict__ counts, int e,
                                             int& base, int& cnt) {
  int run = 0; base = 0; cnt = 0;
#pragma unroll
  for (int i = 0; i < NE; ++i) {
    int c = counts[i];
    if (i == e) { base = run; cnt = c; }
    run += c;
  }
}

// ---------------------------------------------------------------------------
// Fused gate + weight-cvt (r20 structure, best measured: 153.3us) with the
// weight-slice loads moved AFTER the barrier: the stage-drain __syncthreads
// (implicit vmcnt(0)) previously waited on the 4 weight float4 loads too;
// issuing them post-barrier lets their HBM latency hide under the gate math
// instead of extending the barrier. f32 gate math (r20-verified: routing
// identical). gate_w staged once to LDS; counts zeroed by block 0.
// ---------------------------------------------------------------------------
__global__ __launch_bounds__(256) void gate_kernel(
    const float* __restrict__ tokens, const float* __restrict__ gate_w,
    const float* __restrict__ w1f, const float* __restrict__ w2f,
    unsigned short* __restrict__ tokB, unsigned short* __restrict__ w1B,
    unsigned short* __restrict__ w2B, int* __restrict__ eid,
    int* __restrict__ counts)
{
  __shared__ float gw[NE * HDIM];  // 32 KB

  int t = threadIdx.x;
  if (blockIdx.x == 0 && t < NE) counts[t] = 0;

  // stage gate_w -> LDS once (8 x 16B per thread, async DMA)
#pragma unroll
  for (int h = 0; h < 8; ++h) {
    size_t f = (size_t)h * 1024 + (size_t)t * 4;
    gload_lds16(gate_w + f, gw + f);
  }

  // token loads + bf16 store
  int wid  = t >> 6;
  int lane = t & 63;
  int n    = blockIdx.x * 4 + wid;

  const float* trow = tokens + (size_t)n * HDIM;
  float4 x[4];
#pragma unroll
  for (int i = 0; i < 4; ++i)
    x[i] = *(const float4*)(trow + i * 256 + lane * 4);

  unsigned short* drow = tokB + (size_t)n * HDIM;
#pragma unroll
  for (int i = 0; i < 4; ++i) {
    ushort4v o;
    o[0] = f2bf(x[i].x); o[1] = f2bf(x[i].y);
    o[2] = f2bf(x[i].z); o[3] = f2bf(x[i].w);
    *(ushort4v*)(drow + i * 256 + lane * 4) = o;
  }

  __syncthreads();  // gate_w staged (drains stage + token traffic only)

  // weight slice: issue loads NOW -- latency hides under the gate math below
  int b = blockIdx.x;
  const float* wsrc = (b < 2048) ? w1f : w2f;
  unsigned short* wdst = (b < 2048) ? w1B : w2B;
  size_t wi0 = ((size_t)(b & 2047) * 4096) + (size_t)t * 16;
  float4 wf[4];
#pragma unroll
  for (int h = 0; h < 4; ++h)
    wf[h] = *(const float4*)(wsrc + wi0 + h * 4);

  // gate math from LDS (f32 accum)
  float acc[NE];
#pragma unroll
  for (int e = 0; e < NE; ++e) {
    const float* grow = gw + e * HDIM;
    float a = 0.f;
#pragma unroll
    for (int i = 0; i < 4; ++i) {
      float4 g = *(const float4*)(grow + i * 256 + lane * 4);
      a += x[i].x * g.x + x[i].y * g.y + x[i].z * g.z + x[i].w * g.w;
    }
    acc[e] = a;
  }
#pragma unroll
  for (int off = 32; off; off >>= 1) {
#pragma unroll
    for (int e = 0; e < NE; ++e) acc[e] += __shfl_xor(acc[e], off);
  }
  if (lane == 0) {
    int best = 0; float bv = acc[0];
#pragma unroll
    for (int e = 1; e < NE; ++e) if (acc[e] > bv) { bv = acc[e]; best = e; }
    eid[n] = best;
  }

  // weight slice: convert + store (loads have drained under the math)
  {
    ushort8 o0, o1;
    o0[0] = f2bf(wf[0].x); o0[1] = f2bf(wf[0].y); o0[2] = f2bf(wf[0].z); o0[3] = f2bf(wf[0].w);
    o0[4] = f2bf(wf[1].x); o0[5] = f2bf(wf[1].y); o0[6] = f2bf(wf[1].z); o0[7] = f2bf(wf[1].w);
    o1[0] = f2bf(wf[2].x); o1[1] = f2bf(wf[2].y); o1[2] = f2bf(wf[2].z); o1[3] = f2bf(wf[2].w);
    o1[4] = f2bf(wf[3].x); o1[5] = f2bf(wf[3].y); o1[6] = f2bf(wf[3].z); o1[7] = f2bf(wf[3].w);
    *(ushort8*)(wdst + wi0)     = o0;
    *(ushort8*)(wdst + wi0 + 8) = o1;
  }
}

// ---------------------------------------------------------------------------
// Rank: LDS histogram per 256-token block; 8 global atomics per block.
// ---------------------------------------------------------------------------
__global__ __launch_bounds__(256) void rank_kernel(
    const int* __restrict__ eid, int* __restrict__ rank, int* __restrict__ counts)
{
  __shared__ int h[NE];
  __shared__ int bbase[NE];
  int t = threadIdx.x;
  int n = blockIdx.x * 256 + t;
  if (t < NE) h[t] = 0;
  __syncthreads();
  int e = eid[n];
  int r = atomicAdd(&h[e], 1);
  __syncthreads();
  if (t < NE) bbase[t] = atomicAdd(&counts[t], h[t]);
  __syncthreads();
  rank[n] = bbase[e] + r;
}

// perm + tilemap fused (r11-verified): scatter token index; block 0 thread 0
// also emits the compact active-tile list for the GEMM grid.
__global__ __launch_bounds__(256) void perm_kernel(
    const int* __restrict__ counts, const int* __restrict__ eid,
    const int* __restrict__ rank, int* __restrict__ topos,
    int* __restrict__ tmeta)
{
  __shared__ int off[NE];
  int t = threadIdx.x;
  if (t == 0) {
    int run = 0;
#pragma unroll
    for (int e = 0; e < NE; ++e) { off[e] = run; run += counts[e]; }
  }
  __syncthreads();
  int n = blockIdx.x * 256 + t;
  topos[off[eid[n]] + rank[n]] = n;
  if (blockIdx.x == 0 && t == 0) {
    int idx = 0;
    for (int e = 0; e < NE; ++e) {
      int ntile = (counts[e] + BM - 1) / BM;
      for (int mt = 0; mt < ntile; ++mt) tmeta[1 + idx++] = (mt << 3) | e;
    }
    tmeta[0] = idx;
  }
}

// ---------------------------------------------------------------------------
// Grouped GEMM, r5-verified m97 structure: 128x128 tile, BK=64, 4 waves (2x2),
// single 32KB LDS buffer, 2 syncthreads per K-tile, compiler-scheduled waits.
// Both-sides chunk-XOR LDS swizzle (0 conflicts). XCD-chunked block swizzle
// (17 consecutive tiles ~ one expert per XCD; FETCH 141->36 MB).
// ---------------------------------------------------------------------------
#define GEMM_PREAMBLE()                                                        \
  int bid = blockIdx.x;                                                        \
  int logical = (bid & 7) * (GRID_GEMM / 8) + (bid >> 3);                      \
  int tile = logical >> 3;                                                     \
  int nt   = logical & 7;                                                      \
  if (tile >= tmeta[0]) return;                                                \
  int ent = tmeta[1 + tile];                                                   \
  int e = ent & 7, mt = ent >> 3;                                              \
  int base, cnt;                                                               \
  expert_range(counts, e, base, cnt);                                          \
  __shared__ unsigned short Alds[BM * BK];                                     \
  __shared__ unsigned short Blds[BN * BK];                                     \
  int t    = threadIdx.x;                                                      \
  int kc   = t & 7;            /* 16B chunk within row */                      \
  int rowi = t >> 3;           /* 0..31 */                                     \
  int sch  = kc ^ (rowi & 7);  /* inverse-swizzled source chunk */             \
  int lane = t & 63, wid = t >> 6;                                             \
  int wr = wid >> 1, wc = wid & 1;                                             \
  f32x4 acc[4][4] = {};                                                        \
  int arow0 = wr * 64 + (lane & 15);                                           \
  int brow0 = wc * 64 + (lane & 15);                                           \
  int hi    = lane >> 4;       /* 0..3 */                                      \
  int xo    = lane & 7;        /* read-side XOR */

#define GEMM_STAGE(kt)                                                         \
  _Pragma("unroll")                                                            \
  for (int r = 0; r < 4; ++r) {                                                \
    gload_lds16(APTR(r, kt), Alds + t * 8 + 2048 * r);                         \
    gload_lds16(bsrc + (size_t)(kt) * BK + (size_t)(32 * r) * HDIM,            \
                Blds + t * 8 + 2048 * r);                                      \
  }

#define GEMM_COMPUTE()                                                         \
  _Pragma("unroll")                                                            \
  for (int ks = 0; ks < 2; ++ks) {                                             \
    int ch = ((ks * 4 + hi) ^ xo) * 8;                                         \
    bf16x8 af[4], bv[4];                                                       \
    _Pragma("unroll")                                                          \
    for (int m = 0; m < 4; ++m)                                                \
      af[m] = *(const bf16x8*)(Alds + (arow0 + m * 16) * BK + ch);             \
    _Pragma("unroll")                                                          \
    for (int n2 = 0; n2 < 4; ++n2)                                             \
      bv[n2] = *(const bf16x8*)(Blds + (brow0 + n2 * 16) * BK + ch);           \
    _Pragma("unroll")                                                          \
    for (int m = 0; m < 4; ++m)                                                \
      _Pragma("unroll")                                                        \
      for (int n2 = 0; n2 < 4; ++n2)                                           \
        acc[m][n2] = __builtin_amdgcn_mfma_f32_16x16x32_bf16(                  \
            af[m], bv[n2], acc[m][n2], 0, 0, 0);                               \
  }

#define GEMM_MAINLOOP()                                                        \
  for (int kt = 0; kt < NKT; ++kt) {                                           \
    __syncthreads();                                                           \
    GEMM_STAGE(kt);                                                            \
    __syncthreads();                                                           \
    GEMM_COMPUTE();                                                            \
  }

__global__ __launch_bounds__(256) void gemm1_kernel(
    const unsigned short* __restrict__ tokB,  // [N][H] token order
    const unsigned short* __restrict__ w1B,   // [E][H][H]
    const float* __restrict__ b1,             // [E][H]
    const int* __restrict__ counts,
    const int* __restrict__ tmeta,
    const int* __restrict__ topos,
    unsigned short* __restrict__ Hbuf)        // [N][H] compacted
{
  GEMM_PREAMBLE()
  int tokr[4];
#pragma unroll
  for (int r = 0; r < 4; ++r) {
    int pos = base + mt * BM + rowi + 32 * r;
    if (pos > N_TOK - 1) pos = N_TOK - 1;
    tokr[r] = topos[pos];
  }
  const unsigned short* bsrc =
      w1B + ((size_t)e << 20) + (size_t)(nt * BN + rowi) * HDIM + sch * 8;
#define APTR(r, kt) (tokB + (size_t)tokr[r] * HDIM + (kt) * BK + sch * 8)
  GEMM_MAINLOOP()
#undef APTR

  int crow0 = wr * 64 + (lane >> 4) * 4;
  int ccol0 = wc * 64 + (lane & 15);
  float bias[4];
#pragma unroll
  for (int n2 = 0; n2 < 4; ++n2)
    bias[n2] = b1[e * HDIM + nt * BN + ccol0 + n2 * 16];
#pragma unroll
  for (int m = 0; m < 4; ++m) {
#pragma unroll
    for (int j = 0; j < 4; ++j) {
      int row = crow0 + m * 16 + j;
      if (mt * BM + row < cnt) {
        size_t orow = (size_t)(base + mt * BM + row) * HDIM + nt * BN;
#pragma unroll
        for (int n2 = 0; n2 < 4; ++n2) {
          float v = acc[m][n2][j] + bias[n2];
          v = v > 0.f ? v : 0.f;
          Hbuf[orow + ccol0 + n2 * 16] = f2bf(v);
        }
      }
    }
  }
}

__global__ __launch_bounds__(256) void gemm2_kernel(
    const unsigned short* __restrict__ Hbuf,  // [N][H] compacted
    const unsigned short* __restrict__ w2B,   // [E][H][H]
    const float* __restrict__ b2,             // [E][H]
    const int* __restrict__ counts,
    const int* __restrict__ tmeta,
    const int* __restrict__ topos,
    float* __restrict__ out)                  // [N][H] token order
{
  GEMM_PREAMBLE()
  int arows[4];
#pragma unroll
  for (int r = 0; r < 4; ++r) {
    int pos = base + mt * BM + rowi + 32 * r;
    arows[r] = pos > N_TOK - 1 ? N_TOK - 1 : pos;
  }
  const unsigned short* bsrc =
      w2B + ((size_t)e << 20) + (size_t)(nt * BN + rowi) * HDIM + sch * 8;
#define APTR(r, kt) (Hbuf + (size_t)arows[r] * HDIM + (kt) * BK + sch * 8)
  GEMM_MAINLOOP()
#undef APTR

  int crow0 = wr * 64 + (lane >> 4) * 4;
  int ccol0 = wc * 64 + (lane & 15);
  float bias[4];
#pragma unroll
  for (int n2 = 0; n2 < 4; ++n2)
    bias[n2] = b2[e * HDIM + nt * BN + ccol0 + n2 * 16];
#pragma unroll
  for (int m = 0; m < 4; ++m) {
#pragma unroll
    for (int j = 0; j < 4; ++j) {
      int row = crow0 + m * 16 + j;
      if (mt * BM + row < cnt) {
        int tok = topos[base + mt * BM + row];
        size_t orow = (size_t)tok * HDIM + nt * BN;
#pragma unroll
        for (int n2 = 0; n2 < 4; ++n2)
          out[orow + ccol0 + n2 * 16] = acc[m][n2][j] + bias[n2];
      }
    }
  }
}

extern "C" void kernel_launch(void* const* d_in, const int* in_sizes, int n_in,
                              void* d_out, int out_size, void* d_ws, size_t ws_size,
                              hipStream_t stream) {
  (void)in_sizes; (void)n_in; (void)out_size; (void)ws_size;
  const float* tokens = (const float*)d_in[0];
  const float* gate_w = (const float*)d_in[1];
  const float* w1     = (const float*)d_in[2];
  const float* b1     = (const float*)d_in[3];
  const float* w2     = (const float*)d_in[4];
  const float* b2     = (const float*)d_in[5];
  float* out          = (float*)d_out;

  char* ws = (char*)d_ws;
  size_t o = 0;
  int* counts = (int*)(ws + o); o += 256;
  int* tmeta  = (int*)(ws + o); o += 1024;
  int* eid    = (int*)(ws + o); o += (size_t)N_TOK * 4;
  int* rank   = (int*)(ws + o); o += (size_t)N_TOK * 4;
  int* topos  = (int*)(ws + o); o += (size_t)N_TOK * 4;
  unsigned short* tokB = (unsigned short*)(ws + o); o += (size_t)N_TOK * HDIM * 2;
  unsigned short* w1B  = (unsigned short*)(ws + o); o += (size_t)NE * HDIM * HDIM * 2;
  unsigned short* w2B  = (unsigned short*)(ws + o); o += (size_t)NE * HDIM * HDIM * 2;
  unsigned short* Hbuf = (unsigned short*)(ws + o); o += (size_t)N_TOK * HDIM * 2;

  gate_kernel<<<N_TOK / 4, 256, 0, stream>>>(tokens, gate_w, w1, w2,
                                             tokB, w1B, w2B, eid, counts);
  rank_kernel<<<N_TOK / 256, 256, 0, stream>>>(eid, rank, counts);
  perm_kernel<<<N_TOK / 256, 256, 0, stream>>>(counts, eid, rank, topos, tmeta);
  gemm1_kernel<<<GRID_GEMM, 256, 0, stream>>>(tokB, w1B, b1, counts, tmeta, topos, Hbuf);
  gemm2_kernel<<<GRID_GEMM, 256, 0, stream>>>(Hbuf, w2B, b2, counts, tmeta, topos, out);
}